// Round 8
// baseline (83.703 us; speedup 1.0000x reference)
//
#include <hip/hip_runtime.h>

#define BATCH 16384
#define EMBD 64
#define GLOBAL_MEAN 3.82f

typedef unsigned short u16;
typedef unsigned int u32;

__device__ __forceinline__ u16 f32_to_bf16_rne(float f) {
    u32 u = __float_as_uint(f);
    u32 lsb = (u >> 16) & 1u;
    u += 0x7fffu + lsb;
    return (u16)(u >> 16);
}

// --- fused preprocessing: zero rows + bf16 table convert + seg bounds ---
__global__ __launch_bounds__(256) void prep_fused(
    const int* __restrict__ sp_seg, int n_sp, int* __restrict__ sp_start,
    const int* __restrict__ sw_seg, int n_sw, int* __restrict__ sw_start,
    const float* __restrict__ tf, const float* __restrict__ tw,
    u16* __restrict__ f16, u16* __restrict__ w16, int tbl_elems,
    float* __restrict__ zrowf, u16* __restrict__ zrow16)
{
    int gi = blockIdx.x * blockDim.x + threadIdx.x;
    if (gi < EMBD) { zrowf[gi] = 0.0f; zrow16[gi] = 0; }

    const int q = tbl_elems >> 2;          // float4 chunks per table
    if (gi < 2 * q) {
        const float* src = gi < q ? tf : tw;
        u16* dst         = gi < q ? f16 : w16;
        int i            = gi < q ? gi : gi - q;
        float4 v = *(const float4*)(src + (size_t)i * 4);
        ushort4 o;
        o.x = f32_to_bf16_rne(v.x);
        o.y = f32_to_bf16_rne(v.y);
        o.z = f32_to_bf16_rne(v.z);
        o.w = f32_to_bf16_rne(v.w);
        *(ushort4*)(dst + (size_t)i * 4) = o;
        return;
    }
    int i = gi - 2 * q;
    const int* seg; int n; int* start;
    if (i < n_sp) { seg = sp_seg; n = n_sp; start = sp_start; }
    else {
        i -= n_sp;
        if (i >= n_sw) return;
        seg = sw_seg; n = n_sw; start = sw_start;
    }
    int s = seg[i];
    int sprev = (i == 0) ? -1 : seg[i - 1];
    for (int r = sprev + 1; r <= s; ++r) start[r] = i;
    if (i == n - 1)
        for (int r = s + 1; r <= BATCH; ++r) start[r] = n;
}

// ============ main kernel: bf16 tables, 8 lanes x 16B per row ============
// sub = lane>>3 (8 subgroups), each subgroup loads ONE entry row per step;
// each lane covers 8 dims (uint4 = 8 bf16). Per 64-entry chunk: fixed 8-deep
// fully-unrolled gather batch (k = sub+8u <= 63 -> shfl always all-lanes).
__global__ __launch_bounds__(256, 6) void svdpp_fwd_bf16(
    const int* __restrict__ scientist_ids,
    const int* __restrict__ paper_ids,
    const int* __restrict__ sp_idx, const int* __restrict__ sp_start,
    const int* __restrict__ sw_idx, const int* __restrict__ sw_start,
    const float* __restrict__ s_factors,
    const float* __restrict__ p_factors,
    const float* __restrict__ s_bias,
    const float* __restrict__ p_bias,
    const u16* __restrict__ f16,
    const u16* __restrict__ w16,
    const u16* __restrict__ zrow16,
    float* __restrict__ out)
{
    const int wave = (blockIdx.x * blockDim.x + threadIdx.x) >> 6;
    const int lane = threadIdx.x & 63;
    if (wave >= BATCH) return;
    const int row  = wave;
    const int sub  = lane >> 3;        // 8 subgroups of 8 lanes
    const int doff = (lane & 7) * 8;   // this lane's 8 dims

    const int s0 = __builtin_amdgcn_readfirstlane(sp_start[row]);
    const int e0 = __builtin_amdgcn_readfirstlane(sp_start[row + 1]);
    const int s1 = __builtin_amdgcn_readfirstlane(sw_start[row]);
    const int e1 = __builtin_amdgcn_readfirstlane(sw_start[row + 1]);
    const int n0 = e0 - s0;
    const int n1 = e1 - s1;
    const int sid = __builtin_amdgcn_readfirstlane(scientist_ids[row]);
    const int pid = __builtin_amdgcn_readfirstlane(paper_ids[row]);

    float acc0[8] = {0.f,0.f,0.f,0.f,0.f,0.f,0.f,0.f};
    float acc1[8] = {0.f,0.f,0.f,0.f,0.f,0.f,0.f,0.f};

    const int m = n0 > n1 ? n0 : n1;

    #define CVT_ACC(ACC, VV)                                            \
        do {                                                            \
            ACC[0] += __uint_as_float((VV).x << 16);                    \
            ACC[1] += __uint_as_float((VV).x & 0xffff0000u);            \
            ACC[2] += __uint_as_float((VV).y << 16);                    \
            ACC[3] += __uint_as_float((VV).y & 0xffff0000u);            \
            ACC[4] += __uint_as_float((VV).z << 16);                    \
            ACC[5] += __uint_as_float((VV).z & 0xffff0000u);            \
            ACC[6] += __uint_as_float((VV).w << 16);                    \
            ACC[7] += __uint_as_float((VV).w & 0xffff0000u);            \
        } while (0)

    for (int c = 0; c < m; c += 64) {
        // ---- pool 0 (implicit_factors) ----
        int r0 = n0 - c;
        if (r0 > 0) {                       // wave-uniform
            int lim0 = r0 < 64 ? r0 : 64;
            int i0 = s0 + c + lane;
            int a0 = i0 < e0 ? i0 : e0 - 1;
            int my0 = sp_idx[a0];
            uint4 v[8];
            #pragma unroll
            for (int u = 0; u < 8; ++u) {
                int k = sub + 8 * u;        // <= 63 always
                int idx = __shfl(my0, k, 64);
                const u16* base = (k < lim0) ? (f16 + (size_t)idx * EMBD) : zrow16;
                v[u] = *(const uint4*)(base + doff);
            }
            #pragma unroll
            for (int u = 0; u < 8; ++u) CVT_ACC(acc0, v[u]);
        }
        // ---- pool 1 (implicit_wishlist) ----
        int r1 = n1 - c;
        if (r1 > 0) {
            int lim1 = r1 < 64 ? r1 : 64;
            int i1 = s1 + c + lane;
            int a1 = i1 < e1 ? i1 : e1 - 1;
            int my1 = sw_idx[a1];
            uint4 v[8];
            #pragma unroll
            for (int u = 0; u < 8; ++u) {
                int k = sub + 8 * u;
                int idx = __shfl(my1, k, 64);
                const u16* base = (k < lim1) ? (w16 + (size_t)idx * EMBD) : zrow16;
                v[u] = *(const uint4*)(base + doff);
            }
            #pragma unroll
            for (int u = 0; u < 8; ++u) CVT_ACC(acc1, v[u]);
        }
    }
    #undef CVT_ACC

    // combine the 8 subgroups: xor 8,16,32 -> every lane holds full pooled
    // sums for its 8 dims
    #pragma unroll
    for (int d = 0; d < 8; ++d) {
        acc0[d] += __shfl_xor(acc0[d], 8, 64);
        acc0[d] += __shfl_xor(acc0[d], 16, 64);
        acc0[d] += __shfl_xor(acc0[d], 32, 64);
        acc1[d] += __shfl_xor(acc1[d], 8, 64);
        acc1[d] += __shfl_xor(acc1[d], 16, 64);
        acc1[d] += __shfl_xor(acc1[d], 32, 64);
    }

    const float inv0 = n0 > 0 ? rsqrtf((float)n0) : 0.f;
    const float inv1 = n1 > 0 ? rsqrtf((float)n1) : 0.f;

    const float4 sfa = *(const float4*)(s_factors + (size_t)sid * EMBD + doff);
    const float4 sfb = *(const float4*)(s_factors + (size_t)sid * EMBD + doff + 4);
    const float4 pfa = *(const float4*)(p_factors + (size_t)pid * EMBD + doff);
    const float4 pfb = *(const float4*)(p_factors + (size_t)pid * EMBD + doff + 4);
    const float sb = s_bias[sid];
    const float pb = p_bias[pid];

    float v = (sfa.x + acc0[0] * inv0 + acc1[0] * inv1) * pfa.x
            + (sfa.y + acc0[1] * inv0 + acc1[1] * inv1) * pfa.y
            + (sfa.z + acc0[2] * inv0 + acc1[2] * inv1) * pfa.z
            + (sfa.w + acc0[3] * inv0 + acc1[3] * inv1) * pfa.w
            + (sfb.x + acc0[4] * inv0 + acc1[4] * inv1) * pfb.x
            + (sfb.y + acc0[5] * inv0 + acc1[5] * inv1) * pfb.y
            + (sfb.z + acc0[6] * inv0 + acc1[6] * inv1) * pfb.z
            + (sfb.w + acc0[7] * inv0 + acc1[7] * inv1) * pfb.w;

    // reduce across the 8 dim-slots (lanes differing in bits 0..2)
    v += __shfl_xor(v, 1, 64);
    v += __shfl_xor(v, 2, 64);
    v += __shfl_xor(v, 4, 64);

    if (lane == 0)
        out[row] = v + sb + pb + GLOBAL_MEAN;
}

// ================= fallback: f32 gather path =================
__global__ __launch_bounds__(256, 8) void svdpp_fwd_f32(
    const int* __restrict__ scientist_ids,
    const int* __restrict__ paper_ids,
    const int* __restrict__ sp_idx, const int* __restrict__ sp_start,
    const int* __restrict__ sw_idx, const int* __restrict__ sw_start,
    const float* __restrict__ s_factors,
    const float* __restrict__ p_factors,
    const float* __restrict__ s_bias,
    const float* __restrict__ p_bias,
    const float* __restrict__ imp_f,
    const float* __restrict__ imp_w,
    const float* __restrict__ zrow,
    float* __restrict__ out)
{
    const int wave = (blockIdx.x * blockDim.x + threadIdx.x) >> 6;
    const int lane = threadIdx.x & 63;
    if (wave >= BATCH) return;
    const int row  = wave;
    const int sub  = lane >> 4;
    const int doff = (lane & 15) * 4;

    const int s0 = __builtin_amdgcn_readfirstlane(sp_start[row]);
    const int e0 = __builtin_amdgcn_readfirstlane(sp_start[row + 1]);
    const int s1 = __builtin_amdgcn_readfirstlane(sw_start[row]);
    const int e1 = __builtin_amdgcn_readfirstlane(sw_start[row + 1]);
    const int n0 = e0 - s0;
    const int n1 = e1 - s1;

    const int sid = __builtin_amdgcn_readfirstlane(scientist_ids[row]);
    const int pid = __builtin_amdgcn_readfirstlane(paper_ids[row]);
    const float4 sf = *(const float4*)(s_factors + (size_t)sid * EMBD + doff);
    const float4 pf = *(const float4*)(p_factors + (size_t)pid * EMBD + doff);
    const float sb = s_bias[sid];
    const float pb = p_bias[pid];

    float4 acc0 = {0.f, 0.f, 0.f, 0.f};
    float4 acc1 = {0.f, 0.f, 0.f, 0.f};
    const int m = n0 > n1 ? n0 : n1;

    for (int c = 0; c < m; c += 64) {
        int r0 = n0 - c;
        if (r0 > 0) {
            int lim0 = r0 < 64 ? r0 : 64;
            int i0 = s0 + c + lane;
            int a0 = i0 < e0 ? i0 : e0 - 1;
            int my0 = sp_idx[a0];
            int jm = (lim0 + 3) >> 2;
            for (int step = 0; step < jm; step += 8) {
                float4 v[8];
                #pragma unroll
                for (int u = 0; u < 8; ++u) {
                    int k = sub + 4 * (step + u);
                    int idx = __shfl(my0, k, 64);
                    const float* base = (k < lim0) ? (imp_f + (size_t)idx * EMBD) : zrow;
                    v[u] = *(const float4*)(base + doff);
                }
                #pragma unroll
                for (int u = 0; u < 8; ++u) {
                    acc0.x += v[u].x; acc0.y += v[u].y;
                    acc0.z += v[u].z; acc0.w += v[u].w;
                }
            }
        }
        int r1 = n1 - c;
        if (r1 > 0) {
            int lim1 = r1 < 64 ? r1 : 64;
            int i1 = s1 + c + lane;
            int a1 = i1 < e1 ? i1 : e1 - 1;
            int my1 = sw_idx[a1];
            int jm = (lim1 + 3) >> 2;
            for (int step = 0; step < jm; step += 8) {
                float4 v[8];
                #pragma unroll
                for (int u = 0; u < 8; ++u) {
                    int k = sub + 4 * (step + u);
                    int idx = __shfl(my1, k, 64);
                    const float* base = (k < lim1) ? (imp_w + (size_t)idx * EMBD) : zrow;
                    v[u] = *(const float4*)(base + doff);
                }
                #pragma unroll
                for (int u = 0; u < 8; ++u) {
                    acc1.x += v[u].x; acc1.y += v[u].y;
                    acc1.z += v[u].z; acc1.w += v[u].w;
                }
            }
        }
    }

    acc0.x += __shfl_xor(acc0.x, 16, 64); acc0.x += __shfl_xor(acc0.x, 32, 64);
    acc0.y += __shfl_xor(acc0.y, 16, 64); acc0.y += __shfl_xor(acc0.y, 32, 64);
    acc0.z += __shfl_xor(acc0.z, 16, 64); acc0.z += __shfl_xor(acc0.z, 32, 64);
    acc0.w += __shfl_xor(acc0.w, 16, 64); acc0.w += __shfl_xor(acc0.w, 32, 64);
    acc1.x += __shfl_xor(acc1.x, 16, 64); acc1.x += __shfl_xor(acc1.x, 32, 64);
    acc1.y += __shfl_xor(acc1.y, 16, 64); acc1.y += __shfl_xor(acc1.y, 32, 64);
    acc1.z += __shfl_xor(acc1.z, 16, 64); acc1.z += __shfl_xor(acc1.z, 32, 64);
    acc1.w += __shfl_xor(acc1.w, 16, 64); acc1.w += __shfl_xor(acc1.w, 32, 64);

    const float inv0 = n0 > 0 ? rsqrtf((float)n0) : 0.f;
    const float inv1 = n1 > 0 ? rsqrtf((float)n1) : 0.f;

    float v = (sf.x + acc0.x * inv0 + acc1.x * inv1) * pf.x
            + (sf.y + acc0.y * inv0 + acc1.y * inv1) * pf.y
            + (sf.z + acc0.z * inv0 + acc1.z * inv1) * pf.z
            + (sf.w + acc0.w * inv0 + acc1.w * inv1) * pf.w;

    v += __shfl_xor(v, 1, 64);
    v += __shfl_xor(v, 2, 64);
    v += __shfl_xor(v, 4, 64);

    v += __shfl_xor(v, 8, 64);

    if (lane == 0)
        out[row] = v + sb + pb + GLOBAL_MEAN;
}

extern "C" void kernel_launch(void* const* d_in, const int* in_sizes, int n_in,
                              void* d_out, int out_size, void* d_ws, size_t ws_size,
                              hipStream_t stream) {
    const int* scientist_ids = (const int*)d_in[0];
    const int* paper_ids     = (const int*)d_in[1];
    const int* sp_idx        = (const int*)d_in[2];
    const int* sp_seg        = (const int*)d_in[3];
    const int* sw_idx        = (const int*)d_in[4];
    const int* sw_seg        = (const int*)d_in[5];
    const float* s_factors   = (const float*)d_in[6];
    const float* p_factors   = (const float*)d_in[7];
    const float* s_bias      = (const float*)d_in[8];
    const float* p_bias      = (const float*)d_in[9];
    const float* imp_f       = (const float*)d_in[10];
    const float* imp_w       = (const float*)d_in[11];
    float* out = (float*)d_out;

    const int t_sp = in_sizes[2];
    const int t_sw = in_sizes[4];
    const int tbl_elems = in_sizes[10];            // n_papers * 64

    // ws layout:
    // [0,256)       f32 zero row (64 floats)
    // [256,384)     bf16 zero row (64 u16)
    // [512, ...)    sp_start[(B+1)], sw_start[(B+1)]
    // aligned 256:  bf16 tables f16, w16
    char* ws = (char*)d_ws;
    float* zrowf  = (float*)ws;
    u16*   zrow16 = (u16*)(ws + 256);
    int* sp_start = (int*)(ws + 512);
    int* sw_start = sp_start + (BATCH + 1);
    size_t off = 512 + (size_t)2 * (BATCH + 1) * 4;
    off = (off + 255) & ~(size_t)255;
    u16* f16 = (u16*)(ws + off);
    u16* w16 = f16 + (size_t)tbl_elems;
    size_t need = off + (size_t)2 * tbl_elems * 2;

    const int blocks = (BATCH * 64) / 256;

    if (ws_size >= need) {
        const int q = tbl_elems >> 2;
        const int prep_threads = 2 * q + t_sp + t_sw;
        prep_fused<<<(prep_threads + 255) / 256, 256, 0, stream>>>(
            sp_seg, t_sp, sp_start, sw_seg, t_sw, sw_start,
            imp_f, imp_w, f16, w16, tbl_elems, zrowf, zrow16);
        svdpp_fwd_bf16<<<blocks, 256, 0, stream>>>(
            scientist_ids, paper_ids,
            sp_idx, sp_start, sw_idx, sw_start,
            s_factors, p_factors, s_bias, p_bias,
            f16, w16, zrow16, out);
    } else {
        prep_fused<<<(t_sp + t_sw + 255) / 256, 256, 0, stream>>>(
            sp_seg, t_sp, sp_start, sw_seg, t_sw, sw_start,
            imp_f, imp_w, (u16*)zrow16, (u16*)zrow16, 0, zrowf, zrow16);
        svdpp_fwd_f32<<<blocks, 256, 0, stream>>>(
            scientist_ids, paper_ids,
            sp_idx, sp_start, sw_idx, sw_start,
            s_factors, p_factors, s_bias, p_bias,
            imp_f, imp_w, zrowf, out);
    }
}

// Round 9
// 35.818 us; speedup vs baseline: 2.3369x; 2.3369x over previous
//
#include <hip/hip_runtime.h>

#define BATCH 16384
#define EMBD 64
#define GLOBAL_MEAN 3.82f

typedef unsigned short u16;
typedef unsigned int u32;

__device__ __forceinline__ u32 f32_to_bf16_rne_bits(float f) {
    u32 u = __float_as_uint(f);
    u32 lsb = (u >> 16) & 1u;
    u += 0x7fffu + lsb;
    return u >> 16;
}

// --- fused preprocessing: zero rows + bf16 table convert + seg bounds ---
// convert: 8 floats -> one 16B packed bf16 store per thread
__global__ __launch_bounds__(256) void prep_fused(
    const int* __restrict__ sp_seg, int n_sp, int* __restrict__ sp_start,
    const int* __restrict__ sw_seg, int n_sw, int* __restrict__ sw_start,
    const float* __restrict__ tf, const float* __restrict__ tw,
    u16* __restrict__ f16, u16* __restrict__ w16, int tbl_elems,
    float* __restrict__ zrowf, u16* __restrict__ zrow16)
{
    int gi = blockIdx.x * blockDim.x + threadIdx.x;
    if (gi < EMBD) { zrowf[gi] = 0.0f; zrow16[gi] = 0; }

    const int q = tbl_elems >> 3;          // 8-float chunks per table
    if (gi < 2 * q) {
        const float* src = gi < q ? tf : tw;
        u16* dst         = gi < q ? f16 : w16;
        int i            = gi < q ? gi : gi - q;
        float4 a = *(const float4*)(src + (size_t)i * 8);
        float4 b = *(const float4*)(src + (size_t)i * 8 + 4);
        uint4 o;
        o.x = f32_to_bf16_rne_bits(a.x) | (f32_to_bf16_rne_bits(a.y) << 16);
        o.y = f32_to_bf16_rne_bits(a.z) | (f32_to_bf16_rne_bits(a.w) << 16);
        o.z = f32_to_bf16_rne_bits(b.x) | (f32_to_bf16_rne_bits(b.y) << 16);
        o.w = f32_to_bf16_rne_bits(b.z) | (f32_to_bf16_rne_bits(b.w) << 16);
        *(uint4*)(dst + (size_t)i * 8) = o;
        return;
    }
    int i = gi - 2 * q;
    const int* seg; int n; int* start;
    if (i < n_sp) { seg = sp_seg; n = n_sp; start = sp_start; }
    else {
        i -= n_sp;
        if (i >= n_sw) return;
        seg = sw_seg; n = n_sw; start = sw_start;
    }
    int s = seg[i];
    int sprev = (i == 0) ? -1 : seg[i - 1];
    for (int r = sprev + 1; r <= s; ++r) start[r] = i;
    if (i == n - 1)
        for (int r = s + 1; r <= BATCH; ++r) start[r] = n;
}

// ============ main kernel (R7 structure, measured fast) ============
// 16 lanes x ushort4 (8B) per row slice -> each 16-lane coalescing cluster
// covers exactly ONE 128B line. 4 subgroups, 8-deep gather batches.
__global__ __launch_bounds__(256, 6) void svdpp_fwd_bf16(
    const int* __restrict__ scientist_ids,
    const int* __restrict__ paper_ids,
    const int* __restrict__ sp_idx, const int* __restrict__ sp_start,
    const int* __restrict__ sw_idx, const int* __restrict__ sw_start,
    const float* __restrict__ s_factors,
    const float* __restrict__ p_factors,
    const float* __restrict__ s_bias,
    const float* __restrict__ p_bias,
    const u16* __restrict__ f16,
    const u16* __restrict__ w16,
    const u16* __restrict__ zrow16,
    float* __restrict__ out)
{
    const int wave = (blockIdx.x * blockDim.x + threadIdx.x) >> 6;
    const int lane = threadIdx.x & 63;
    if (wave >= BATCH) return;
    const int row  = wave;
    const int sub  = lane >> 4;        // 4 subgroups of 16 lanes
    const int doff = (lane & 15) * 4;  // this lane's 4 dims

    const int s0 = __builtin_amdgcn_readfirstlane(sp_start[row]);
    const int e0 = __builtin_amdgcn_readfirstlane(sp_start[row + 1]);
    const int s1 = __builtin_amdgcn_readfirstlane(sw_start[row]);
    const int e1 = __builtin_amdgcn_readfirstlane(sw_start[row + 1]);
    const int n0 = e0 - s0;
    const int n1 = e1 - s1;

    const int sid = __builtin_amdgcn_readfirstlane(scientist_ids[row]);
    const int pid = __builtin_amdgcn_readfirstlane(paper_ids[row]);
    const float4 sf = *(const float4*)(s_factors + (size_t)sid * EMBD + doff);
    const float4 pf = *(const float4*)(p_factors + (size_t)pid * EMBD + doff);
    const float sb = s_bias[sid];
    const float pb = p_bias[pid];

    float4 acc0 = {0.f, 0.f, 0.f, 0.f};
    float4 acc1 = {0.f, 0.f, 0.f, 0.f};

    const int m = n0 > n1 ? n0 : n1;

    for (int c = 0; c < m; c += 64) {
        // ---- pool 0 (implicit_factors, bf16) ----
        int r0 = n0 - c;
        if (r0 > 0) {
            int lim0 = r0 < 64 ? r0 : 64;
            int i0 = s0 + c + lane;
            int a0 = i0 < e0 ? i0 : e0 - 1;
            int my0 = sp_idx[a0];
            int jm = (lim0 + 3) >> 2;
            for (int step = 0; step < jm; step += 8) {
                ushort4 v[8];
                #pragma unroll
                for (int u = 0; u < 8; ++u) {
                    int k = sub + 4 * (step + u);     // <= 63 always
                    int idx = __shfl(my0, k, 64);     // all lanes active
                    const u16* base = (k < lim0) ? (f16 + (size_t)idx * EMBD) : zrow16;
                    v[u] = *(const ushort4*)(base + doff);
                }
                #pragma unroll
                for (int u = 0; u < 8; ++u) {
                    acc0.x += __uint_as_float(((u32)v[u].x) << 16);
                    acc0.y += __uint_as_float(((u32)v[u].y) << 16);
                    acc0.z += __uint_as_float(((u32)v[u].z) << 16);
                    acc0.w += __uint_as_float(((u32)v[u].w) << 16);
                }
            }
        }
        // ---- pool 1 (implicit_wishlist, bf16) ----
        int r1 = n1 - c;
        if (r1 > 0) {
            int lim1 = r1 < 64 ? r1 : 64;
            int i1 = s1 + c + lane;
            int a1 = i1 < e1 ? i1 : e1 - 1;
            int my1 = sw_idx[a1];
            int jm = (lim1 + 3) >> 2;
            for (int step = 0; step < jm; step += 8) {
                ushort4 v[8];
                #pragma unroll
                for (int u = 0; u < 8; ++u) {
                    int k = sub + 4 * (step + u);
                    int idx = __shfl(my1, k, 64);
                    const u16* base = (k < lim1) ? (w16 + (size_t)idx * EMBD) : zrow16;
                    v[u] = *(const ushort4*)(base + doff);
                }
                #pragma unroll
                for (int u = 0; u < 8; ++u) {
                    acc1.x += __uint_as_float(((u32)v[u].x) << 16);
                    acc1.y += __uint_as_float(((u32)v[u].y) << 16);
                    acc1.z += __uint_as_float(((u32)v[u].z) << 16);
                    acc1.w += __uint_as_float(((u32)v[u].w) << 16);
                }
            }
        }
    }

    acc0.x += __shfl_xor(acc0.x, 16, 64); acc0.x += __shfl_xor(acc0.x, 32, 64);
    acc0.y += __shfl_xor(acc0.y, 16, 64); acc0.y += __shfl_xor(acc0.y, 32, 64);
    acc0.z += __shfl_xor(acc0.z, 16, 64); acc0.z += __shfl_xor(acc0.z, 32, 64);
    acc0.w += __shfl_xor(acc0.w, 16, 64); acc0.w += __shfl_xor(acc0.w, 32, 64);
    acc1.x += __shfl_xor(acc1.x, 16, 64); acc1.x += __shfl_xor(acc1.x, 32, 64);
    acc1.y += __shfl_xor(acc1.y, 16, 64); acc1.y += __shfl_xor(acc1.y, 32, 64);
    acc1.z += __shfl_xor(acc1.z, 16, 64); acc1.z += __shfl_xor(acc1.z, 32, 64);
    acc1.w += __shfl_xor(acc1.w, 16, 64); acc1.w += __shfl_xor(acc1.w, 32, 64);

    const float inv0 = n0 > 0 ? rsqrtf((float)n0) : 0.f;
    const float inv1 = n1 > 0 ? rsqrtf((float)n1) : 0.f;

    float v = (sf.x + acc0.x * inv0 + acc1.x * inv1) * pf.x
            + (sf.y + acc0.y * inv0 + acc1.y * inv1) * pf.y
            + (sf.z + acc0.z * inv0 + acc1.z * inv1) * pf.z
            + (sf.w + acc0.w * inv0 + acc1.w * inv1) * pf.w;

    v += __shfl_xor(v, 1, 64);
    v += __shfl_xor(v, 2, 64);
    v += __shfl_xor(v, 4, 64);
    v += __shfl_xor(v, 8, 64);

    if (lane == 0)
        out[row] = v + sb + pb + GLOBAL_MEAN;
}

// ================= fallback: f32 gather path =================
__global__ __launch_bounds__(256, 8) void svdpp_fwd_f32(
    const int* __restrict__ scientist_ids,
    const int* __restrict__ paper_ids,
    const int* __restrict__ sp_idx, const int* __restrict__ sp_start,
    const int* __restrict__ sw_idx, const int* __restrict__ sw_start,
    const float* __restrict__ s_factors,
    const float* __restrict__ p_factors,
    const float* __restrict__ s_bias,
    const float* __restrict__ p_bias,
    const float* __restrict__ imp_f,
    const float* __restrict__ imp_w,
    const float* __restrict__ zrow,
    float* __restrict__ out)
{
    const int wave = (blockIdx.x * blockDim.x + threadIdx.x) >> 6;
    const int lane = threadIdx.x & 63;
    if (wave >= BATCH) return;
    const int row  = wave;
    const int sub  = lane >> 4;
    const int doff = (lane & 15) * 4;

    const int s0 = __builtin_amdgcn_readfirstlane(sp_start[row]);
    const int e0 = __builtin_amdgcn_readfirstlane(sp_start[row + 1]);
    const int s1 = __builtin_amdgcn_readfirstlane(sw_start[row]);
    const int e1 = __builtin_amdgcn_readfirstlane(sw_start[row + 1]);
    const int n0 = e0 - s0;
    const int n1 = e1 - s1;

    const int sid = __builtin_amdgcn_readfirstlane(scientist_ids[row]);
    const int pid = __builtin_amdgcn_readfirstlane(paper_ids[row]);
    const float4 sf = *(const float4*)(s_factors + (size_t)sid * EMBD + doff);
    const float4 pf = *(const float4*)(p_factors + (size_t)pid * EMBD + doff);
    const float sb = s_bias[sid];
    const float pb = p_bias[pid];

    float4 acc0 = {0.f, 0.f, 0.f, 0.f};
    float4 acc1 = {0.f, 0.f, 0.f, 0.f};
    const int m = n0 > n1 ? n0 : n1;

    for (int c = 0; c < m; c += 64) {
        int r0 = n0 - c;
        if (r0 > 0) {
            int lim0 = r0 < 64 ? r0 : 64;
            int i0 = s0 + c + lane;
            int a0 = i0 < e0 ? i0 : e0 - 1;
            int my0 = sp_idx[a0];
            int jm = (lim0 + 3) >> 2;
            for (int step = 0; step < jm; step += 8) {
                float4 v[8];
                #pragma unroll
                for (int u = 0; u < 8; ++u) {
                    int k = sub + 4 * (step + u);
                    int idx = __shfl(my0, k, 64);
                    const float* base = (k < lim0) ? (imp_f + (size_t)idx * EMBD) : zrow;
                    v[u] = *(const float4*)(base + doff);
                }
                #pragma unroll
                for (int u = 0; u < 8; ++u) {
                    acc0.x += v[u].x; acc0.y += v[u].y;
                    acc0.z += v[u].z; acc0.w += v[u].w;
                }
            }
        }
        int r1 = n1 - c;
        if (r1 > 0) {
            int lim1 = r1 < 64 ? r1 : 64;
            int i1 = s1 + c + lane;
            int a1 = i1 < e1 ? i1 : e1 - 1;
            int my1 = sw_idx[a1];
            int jm = (lim1 + 3) >> 2;
            for (int step = 0; step < jm; step += 8) {
                float4 v[8];
                #pragma unroll
                for (int u = 0; u < 8; ++u) {
                    int k = sub + 4 * (step + u);
                    int idx = __shfl(my1, k, 64);
                    const float* base = (k < lim1) ? (imp_w + (size_t)idx * EMBD) : zrow;
                    v[u] = *(const float4*)(base + doff);
                }
                #pragma unroll
                for (int u = 0; u < 8; ++u) {
                    acc1.x += v[u].x; acc1.y += v[u].y;
                    acc1.z += v[u].z; acc1.w += v[u].w;
                }
            }
        }
    }

    acc0.x += __shfl_xor(acc0.x, 16, 64); acc0.x += __shfl_xor(acc0.x, 32, 64);
    acc0.y += __shfl_xor(acc0.y, 16, 64); acc0.y += __shfl_xor(acc0.y, 32, 64);
    acc0.z += __shfl_xor(acc0.z, 16, 64); acc0.z += __shfl_xor(acc0.z, 32, 64);
    acc0.w += __shfl_xor(acc0.w, 16, 64); acc0.w += __shfl_xor(acc0.w, 32, 64);
    acc1.x += __shfl_xor(acc1.x, 16, 64); acc1.x += __shfl_xor(acc1.x, 32, 64);
    acc1.y += __shfl_xor(acc1.y, 16, 64); acc1.y += __shfl_xor(acc1.y, 32, 64);
    acc1.z += __shfl_xor(acc1.z, 16, 64); acc1.z += __shfl_xor(acc1.z, 32, 64);
    acc1.w += __shfl_xor(acc1.w, 16, 64); acc1.w += __shfl_xor(acc1.w, 32, 64);

    const float inv0 = n0 > 0 ? rsqrtf((float)n0) : 0.f;
    const float inv1 = n1 > 0 ? rsqrtf((float)n1) : 0.f;

    float v = (sf.x + acc0.x * inv0 + acc1.x * inv1) * pf.x
            + (sf.y + acc0.y * inv0 + acc1.y * inv1) * pf.y
            + (sf.z + acc0.z * inv0 + acc1.z * inv1) * pf.z
            + (sf.w + acc0.w * inv0 + acc1.w * inv1) * pf.w;

    v += __shfl_xor(v, 1, 64);
    v += __shfl_xor(v, 2, 64);
    v += __shfl_xor(v, 4, 64);
    v += __shfl_xor(v, 8, 64);

    if (lane == 0)
        out[row] = v + sb + pb + GLOBAL_MEAN;
}

extern "C" void kernel_launch(void* const* d_in, const int* in_sizes, int n_in,
                              void* d_out, int out_size, void* d_ws, size_t ws_size,
                              hipStream_t stream) {
    const int* scientist_ids = (const int*)d_in[0];
    const int* paper_ids     = (const int*)d_in[1];
    const int* sp_idx        = (const int*)d_in[2];
    const int* sp_seg        = (const int*)d_in[3];
    const int* sw_idx        = (const int*)d_in[4];
    const int* sw_seg        = (const int*)d_in[5];
    const float* s_factors   = (const float*)d_in[6];
    const float* p_factors   = (const float*)d_in[7];
    const float* s_bias      = (const float*)d_in[8];
    const float* p_bias      = (const float*)d_in[9];
    const float* imp_f       = (const float*)d_in[10];
    const float* imp_w       = (const float*)d_in[11];
    float* out = (float*)d_out;

    const int t_sp = in_sizes[2];
    const int t_sw = in_sizes[4];
    const int tbl_elems = in_sizes[10];            // n_papers * 64

    // ws layout:
    // [0,256)       f32 zero row (64 floats)
    // [256,384)     bf16 zero row (64 u16)
    // [512, ...)    sp_start[(B+1)], sw_start[(B+1)]
    // aligned 256:  bf16 tables f16, w16
    char* ws = (char*)d_ws;
    float* zrowf  = (float*)ws;
    u16*   zrow16 = (u16*)(ws + 256);
    int* sp_start = (int*)(ws + 512);
    int* sw_start = sp_start + (BATCH + 1);
    size_t off = 512 + (size_t)2 * (BATCH + 1) * 4;
    off = (off + 255) & ~(size_t)255;
    u16* f16 = (u16*)(ws + off);
    u16* w16 = f16 + (size_t)tbl_elems;
    size_t need = off + (size_t)2 * tbl_elems * 2;

    const int blocks = (BATCH * 64) / 256;

    if (ws_size >= need) {
        const int q = tbl_elems >> 3;                  // 8-float chunks
        const int prep_threads = 2 * q + t_sp + t_sw;
        prep_fused<<<(prep_threads + 255) / 256, 256, 0, stream>>>(
            sp_seg, t_sp, sp_start, sw_seg, t_sw, sw_start,
            imp_f, imp_w, f16, w16, tbl_elems, zrowf, zrow16);
        svdpp_fwd_bf16<<<blocks, 256, 0, stream>>>(
            scientist_ids, paper_ids,
            sp_idx, sp_start, sw_idx, sw_start,
            s_factors, p_factors, s_bias, p_bias,
            f16, w16, zrow16, out);
    } else {
        prep_fused<<<(t_sp + t_sw + 255) / 256, 256, 0, stream>>>(
            sp_seg, t_sp, sp_start, sw_seg, t_sw, sw_start,
            imp_f, imp_w, zrow16, zrow16, 0, zrowf, zrow16);
        svdpp_fwd_f32<<<blocks, 256, 0, stream>>>(
            scientist_ids, paper_ids,
            sp_idx, sp_start, sw_idx, sw_start,
            s_factors, p_factors, s_bias, p_bias,
            imp_f, imp_w, zrowf, out);
    }
}